// Round 5
// baseline (435.983 us; speedup 1.0000x reference)
//
#include <hip/hip_runtime.h>

#define N_SIG 2048
#define NT    32           // 2048/64 tiles per dimension
#define N_PAIR_BLOCKS 1056 // (32*33/2) tiles * 2 half-blocks

__device__ __forceinline__ float frcp(float x) { return __builtin_amdgcn_rcpf(x); }

// erf(y / sqrt(2)) — Abramowitz–Stegun 7.1.26 with sqrt2 folded in, |err| < 1.5e-7
__device__ __forceinline__ float erf_div_sqrt2(float y) {
    const float ay = fabsf(y);
    const float t  = frcp(fmaf(0.23164454f, ay, 1.f));   // p/sqrt2, p = 0.3275911
    const float p  = t * fmaf(t, fmaf(t, fmaf(t, fmaf(t, 1.061405429f, -1.453152027f),
                                              1.421413741f), -0.284496736f), 0.254829592f);
    const float e  = __expf(-0.5f * ay * ay);
    return copysignf(fmaf(-p, e, 1.f), y);
}

// ---------------- Kernel 1: per-signal derived quantities + zero acc ----------------
__global__ void derive_k(const float* __restrict__ p, float* __restrict__ dv,
                         float* __restrict__ acc) {
    int j = blockIdx.x * blockDim.x + threadIdx.x;
    if (j >= N_SIG) return;
    #pragma unroll
    for (int k = 0; k < 9; k++) acc[j * 9 + k] = 0.f;
    const float* pj = p + j * 15;
    float m1 = pj[0] * 95.f + 5.f, m2 = pj[1] * 95.f + 5.f;
    float mc = powf(m1 * m2, 0.6f) / powf(m1 + m2, 0.2f);
    float fisco = 220.f / (m1 + m2);
    float dist = pj[2] * 2950.f + 50.f;
    float4* o = (float4*)(dv + j * 8);
    o[0] = make_float4(pj[5], pj[3], pj[4], mc);   // t, ra, dec, mc
    o[1] = make_float4(fisco, dist, pj[7], 0.f);   // fisco, dist, psi, pad
}

// ---------------- Kernel 2: symmetric pair tiles ----------------
__global__ __launch_bounds__(256, 4) void pair_k(
    const float* __restrict__ dv,
    const float* __restrict__ iw1, const float* __restrict__ ib1,
    const float* __restrict__ ig1, const float* __restrict__ ibt1,
    const float* __restrict__ iw2,
    float* __restrict__ acc)
{
    __shared__ float4 sColA[64], sColB[64];
    __shared__ __align__(16) float sW1[128];   // iw1 [16][8]
    __shared__ __align__(16) float sEC[64];    // per-h (b1, g1, bt1, 0.5*w2)
    __shared__ float part[9 * 256];            // [k][wave][lane]

    // ---- tile decode: blockIdx -> (ti <= tj) upper-triangle tile + half ----
    int b = blockIdx.x;
    int tileId = b >> 1;
    const int half = b & 1;
    int k = tileId, ti = 0;
    while (true) { int cnt = NT - ti; if (k < cnt) break; k -= cnt; ti++; }
    const int tj = ti + k;
    const int rbase = ti * 64, cbase = tj * 64;
    const bool diag = (ti == tj);

    const int tid = threadIdx.x;
    const float4* dv4 = (const float4*)dv;

    if (tid < 64)  { sColA[tid] = dv4[(cbase + tid) * 2]; sColB[tid] = dv4[(cbase + tid) * 2 + 1]; }
    if (tid >= 64 && tid < 192) sW1[tid - 64] = iw1[tid - 64];
    if (tid >= 192 && tid < 208) {
        int h = tid - 192;
        sEC[h * 4 + 0] = ib1[h]; sEC[h * 4 + 1] = ig1[h];
        sEC[h * 4 + 2] = ibt1[h]; sEC[h * 4 + 3] = 0.5f * iw2[h];
    }
    __syncthreads();

    const int w = tid >> 6, l = tid & 63;
    const int V = half * 4 + w;          // virtual wave 0..7
    const int gi = rbase + l;
    const float4 r0 = dv4[gi * 2], r1 = dv4[gi * 2 + 1];
    const float ti_ = r0.x, rai = r0.y, deci = r0.z, mci = r0.w;
    const float fi = r1.x, disti = r1.y, psii = r1.z;

    const int nsteps = diag ? 4 : 8;
    const int sbase  = diag ? (V + 1) : V;   // diag covers s in 1..32, off-diag 0..63

    float rowacc[9], colacc[9];
    #pragma unroll
    for (int q = 0; q < 9; q++) { rowacc[q] = 0.f; colacc[q] = 0.f; }

    const float4* sW4  = (const float4*)sW1;
    const float4* sEC4 = (const float4*)sEC;

    for (int t = 0; t < nsteps; t++) {
        const int s  = sbase + 8 * t;
        const int dj = (l + s) & 63;
        const float4 c0 = sColA[dj], c1 = sColB[dj];

        // ---- symmetric pairwise features ----
        const float dra  = fabsf(rai - c0.y), ddec = fabsf(deci - c0.z);
        float f[8];
        f[0] = fabsf(ti_ - c0.x);
        f[1] = __builtin_amdgcn_sqrtf(fmaf(dra, dra, ddec * ddec));
        f[2] = frcp(fmaf(fabsf(mci - c0.w), 0.033333333f, 1.f));
        f[3] = __expf(fabsf(fi - c1.x) * -0.01f);
        f[4] = fminf(disti, c1.y) * frcp(fmaxf(disti, c1.y));
        f[5] = fabsf(psii - c1.z);
        f[6] = dra; f[7] = ddec;

        // ---- 8->16 GEMV + fused moments ----
        float z[16];
        float s1 = 0.f, s2 = 0.f;
        #pragma unroll
        for (int h = 0; h < 16; h++) {
            const float4 w0 = sW4[h * 2];
            const float4 w1 = sW4[h * 2 + 1];
            float zv = sEC4[h].x;
            zv = fmaf(w0.x, f[0], zv); zv = fmaf(w0.y, f[1], zv);
            zv = fmaf(w0.z, f[2], zv); zv = fmaf(w0.w, f[3], zv);
            zv = fmaf(w1.x, f[4], zv); zv = fmaf(w1.y, f[5], zv);
            zv = fmaf(w1.z, f[6], zv); zv = fmaf(w1.w, f[7], zv);
            z[h] = zv;
            s1 += zv; s2 = fmaf(zv, zv, s2);
        }
        const float mu  = s1 * 0.0625f;
        const float var = fmaf(-mu, mu, s2 * 0.0625f);
        const float inv = __builtin_amdgcn_rsqf(var + 1e-5f);

        // ---- GELU(erf) + dot(iw2) ----
        float logit = 0.f;
        #pragma unroll
        for (int h = 0; h < 16; h++) {
            const float4 c = sEC4[h];  // (b, g, bt, 0.5*w2)
            const float y = fmaf((z[h] - mu) * inv, c.y, c.z);
            logit = fmaf(y * c.w, 1.f + erf_div_sqrt2(y), logit);
        }
        float e = __expf(logit);
        // diag tile: s=32 pairs appear twice (lane a and lane a+32) -> keep half
        if (diag && s == 32 && l >= 32) e = 0.f;

        rowacc[8] += e; colacc[8] += e;
        #pragma unroll
        for (int q = 0; q < 8; q++) {
            rowacc[q] = fmaf(e, f[q], rowacc[q]);
            colacc[q] = fmaf(e, f[q], colacc[q]);
        }
        // rotate col accumulator so lane l tracks column (l + s_next) & 63
        if (t + 1 < nsteps) {
            const int src = (l + 8) & 63;
            #pragma unroll
            for (int q = 0; q < 9; q++) colacc[q] = __shfl(colacc[q], src);
        }
    }

    // ---- row-side reduce across the 4 waves, then atomic scatter ----
    #pragma unroll
    for (int q = 0; q < 9; q++) part[q * 256 + w * 64 + l] = rowacc[q];
    __syncthreads();
    if (tid < 64) {
        #pragma unroll
        for (int q = 0; q < 9; q++) {
            const float* pp = part + q * 256 + tid;
            atomicAdd(&acc[(rbase + tid) * 9 + q], pp[0] + pp[64] + pp[128] + pp[192]);
        }
    }
    __syncthreads();

    // ---- col-side: un-rotate to true column index, reduce, scatter ----
    const int s_last = sbase + 8 * (nsteps - 1);
    const int cfin = (l + s_last) & 63;
    #pragma unroll
    for (int q = 0; q < 9; q++) part[q * 256 + w * 64 + cfin] = colacc[q];
    __syncthreads();
    if (tid < 64) {
        #pragma unroll
        for (int q = 0; q < 9; q++) {
            const float* pp = part + q * 256 + tid;
            atomicAdd(&acc[(cbase + tid) * 9 + q], pp[0] + pp[64] + pp[128] + pp[192]);
        }
    }
}

// ---------------- Kernel 3: overlap net per row ----------------
__global__ void out_k(const float* __restrict__ acc,
                      const float* __restrict__ ow1, const float* __restrict__ ob1,
                      const float* __restrict__ og1, const float* __restrict__ obt1,
                      const float* __restrict__ ow2, const float* __restrict__ ob2,
                      float* __restrict__ out)
{
    __shared__ float h2s[32];
    const int i = blockIdx.x, t = threadIdx.x;   // 64 threads
    if (t < 32) {
        const float invL = frcp(acc[i * 9 + 8]);
        float z2 = ob1[t];
        #pragma unroll
        for (int f = 0; f < 8; f++) z2 = fmaf(ow1[t * 8 + f], acc[i * 9 + f] * invL, z2);
        float mu = z2;
        #pragma unroll
        for (int off = 16; off > 0; off >>= 1) mu += __shfl_xor(mu, off);
        mu *= (1.f / 32.f);
        const float d = z2 - mu;
        float var = d * d;
        #pragma unroll
        for (int off = 16; off > 0; off >>= 1) var += __shfl_xor(var, off);
        var *= (1.f / 32.f);
        const float y = d * __builtin_amdgcn_rsqf(var + 1e-5f) * og1[t] + obt1[t];
        h2s[t] = 0.5f * y * (1.f + erf_div_sqrt2(y));
    }
    __syncthreads();
    if (t < 16) {
        float o = ob2[t];
        #pragma unroll
        for (int k = 0; k < 32; k++) o = fmaf(ow2[t * 32 + k], h2s[k], o);
        out[i * 16 + t] = o;
    }
}

extern "C" void kernel_launch(void* const* d_in, const int* in_sizes, int n_in,
                              void* d_out, int out_size, void* d_ws, size_t ws_size,
                              hipStream_t stream) {
    const float* p    = (const float*)d_in[0];
    const float* iw1  = (const float*)d_in[1];
    const float* ib1  = (const float*)d_in[2];
    const float* ig1  = (const float*)d_in[3];
    const float* ibt1 = (const float*)d_in[4];
    const float* iw2  = (const float*)d_in[5];
    // d_in[6] = ib2: uniform logit offset, softmax-invariant -> unused
    const float* ow1  = (const float*)d_in[7];
    const float* ob1  = (const float*)d_in[8];
    const float* og1  = (const float*)d_in[9];
    const float* obt1 = (const float*)d_in[10];
    const float* ow2  = (const float*)d_in[11];
    const float* ob2  = (const float*)d_in[12];

    float* dv  = (float*)d_ws;                 // [2048][8]
    float* acc = (float*)d_ws + N_SIG * 8;     // [2048][9] (sum e*f, sum e)

    derive_k<<<N_SIG / 256, 256, 0, stream>>>(p, dv, acc);
    pair_k<<<N_PAIR_BLOCKS, 256, 0, stream>>>(dv, iw1, ib1, ig1, ibt1, iw2, acc);
    out_k<<<N_SIG, 64, 0, stream>>>(acc, ow1, ob1, og1, obt1, ow2, ob2,
                                    (float*)d_out);
}

// Round 6
// 406.263 us; speedup vs baseline: 1.0732x; 1.0732x over previous
//
#include <hip/hip_runtime.h>

#define N_SIG 2048
#define NT    32           // 2048/64 tiles per dimension
#define N_PAIR_BLOCKS 1056 // (32*33/2) tiles * 2 half-blocks

__device__ __forceinline__ float frcp(float x) { return __builtin_amdgcn_rcpf(x); }

// erf(y / sqrt(2)) — Abramowitz–Stegun 7.1.26 with sqrt2 folded in, |err| < 1.5e-7
__device__ __forceinline__ float erf_div_sqrt2(float y) {
    const float ay = fabsf(y);
    const float t  = frcp(fmaf(0.23164454f, ay, 1.f));   // p/sqrt2, p = 0.3275911
    const float p  = t * fmaf(t, fmaf(t, fmaf(t, fmaf(t, 1.061405429f, -1.453152027f),
                                              1.421413741f), -0.284496736f), 0.254829592f);
    const float e  = __expf(-0.5f * ay * ay);
    return copysignf(fmaf(-p, e, 1.f), y);
}

// ---------------- Kernel 1: per-signal derived quantities + zero acc ----------------
__global__ void derive_k(const float* __restrict__ p, float* __restrict__ dv,
                         float* __restrict__ acc) {
    int j = blockIdx.x * blockDim.x + threadIdx.x;
    if (j >= N_SIG) return;
    #pragma unroll
    for (int k = 0; k < 9; k++) acc[j * 9 + k] = 0.f;
    const float* pj = p + j * 15;
    float m1 = pj[0] * 95.f + 5.f, m2 = pj[1] * 95.f + 5.f;
    float mc = powf(m1 * m2, 0.6f) / powf(m1 + m2, 0.2f);
    float fisco = 220.f / (m1 + m2);
    float dist = pj[2] * 2950.f + 50.f;
    float4* o = (float4*)(dv + j * 8);
    o[0] = make_float4(pj[5], pj[3], pj[4], mc);   // t, ra, dec, mc
    o[1] = make_float4(fisco, dist, pj[7], 0.f);   // fisco, dist, psi, pad
}

// ---------------- Kernel 2: symmetric pair tiles ----------------
__global__ __launch_bounds__(256, 4) void pair_k(
    const float* __restrict__ dv,
    const float* __restrict__ iw1, const float* __restrict__ ib1,
    const float* __restrict__ ig1, const float* __restrict__ ibt1,
    const float* __restrict__ iw2,
    float* __restrict__ acc)
{
    __shared__ float4 sColA[64], sColB[64];
    __shared__ __align__(16) float sW1[128];   // iw1 [16][8]
    __shared__ __align__(16) float sEC[64];    // per-h (b1, g1, bt1, 0.5*w2)
    __shared__ float part[9 * 256];            // [k][wave][lane]

    // ---- tile decode: blockIdx -> (ti <= tj) upper-triangle tile + half ----
    int b = blockIdx.x;
    int tileId = b >> 1;
    const int half = b & 1;
    int k = tileId, ti = 0;
    while (true) { int cnt = NT - ti; if (k < cnt) break; k -= cnt; ti++; }
    const int tj = ti + k;
    const int rbase = ti * 64, cbase = tj * 64;
    const bool diag = (ti == tj);

    const int tid = threadIdx.x;
    const float4* dv4 = (const float4*)dv;

    if (tid < 64)  { sColA[tid] = dv4[(cbase + tid) * 2]; sColB[tid] = dv4[(cbase + tid) * 2 + 1]; }
    if (tid >= 64 && tid < 192) sW1[tid - 64] = iw1[tid - 64];
    if (tid >= 192 && tid < 208) {
        int h = tid - 192;
        sEC[h * 4 + 0] = ib1[h]; sEC[h * 4 + 1] = ig1[h];
        sEC[h * 4 + 2] = ibt1[h]; sEC[h * 4 + 3] = 0.5f * iw2[h];
    }
    __syncthreads();

    const int w = tid >> 6, l = tid & 63;
    const int V = half * 4 + w;          // virtual wave 0..7
    const int gi = rbase + l;
    const float4 r0 = dv4[gi * 2], r1 = dv4[gi * 2 + 1];
    const float ti_ = r0.x, rai = r0.y, deci = r0.z, mci = r0.w;
    const float fi = r1.x, disti = r1.y, psii = r1.z;

    const int nsteps = diag ? 4 : 8;
    const int sbase  = diag ? (V + 1) : V;   // diag covers s in 1..32, off-diag 0..63

    float rowacc[9], colacc[9];
    #pragma unroll
    for (int q = 0; q < 9; q++) { rowacc[q] = 0.f; colacc[q] = 0.f; }

    const float4* sW4  = (const float4*)sW1;
    const float4* sEC4 = (const float4*)sEC;

    for (int t = 0; t < nsteps; t++) {
        const int s  = sbase + 8 * t;
        const int dj = (l + s) & 63;
        const float4 c0 = sColA[dj], c1 = sColB[dj];

        // ---- symmetric pairwise features ----
        const float dra  = fabsf(rai - c0.y), ddec = fabsf(deci - c0.z);
        float f[8];
        f[0] = fabsf(ti_ - c0.x);
        f[1] = __builtin_amdgcn_sqrtf(fmaf(dra, dra, ddec * ddec));
        f[2] = frcp(fmaf(fabsf(mci - c0.w), 0.033333333f, 1.f));
        f[3] = __expf(fabsf(fi - c1.x) * -0.01f);
        f[4] = fminf(disti, c1.y) * frcp(fmaxf(disti, c1.y));
        f[5] = fabsf(psii - c1.z);
        f[6] = dra; f[7] = ddec;

        // ---- 8->16 GEMV + fused moments ----
        float z[16];
        float s1 = 0.f, s2 = 0.f;
        #pragma unroll
        for (int h = 0; h < 16; h++) {
            const float4 w0 = sW4[h * 2];
            const float4 w1 = sW4[h * 2 + 1];
            float zv = sEC4[h].x;
            zv = fmaf(w0.x, f[0], zv); zv = fmaf(w0.y, f[1], zv);
            zv = fmaf(w0.z, f[2], zv); zv = fmaf(w0.w, f[3], zv);
            zv = fmaf(w1.x, f[4], zv); zv = fmaf(w1.y, f[5], zv);
            zv = fmaf(w1.z, f[6], zv); zv = fmaf(w1.w, f[7], zv);
            z[h] = zv;
            s1 += zv; s2 = fmaf(zv, zv, s2);
        }
        const float mu  = s1 * 0.0625f;
        const float var = fmaf(-mu, mu, s2 * 0.0625f);
        const float inv = __builtin_amdgcn_rsqf(var + 1e-5f);

        // ---- GELU(erf) + dot(iw2) ----
        float logit = 0.f;
        #pragma unroll
        for (int h = 0; h < 16; h++) {
            const float4 c = sEC4[h];  // (b, g, bt, 0.5*w2)
            const float y = fmaf((z[h] - mu) * inv, c.y, c.z);
            logit = fmaf(y * c.w, 1.f + erf_div_sqrt2(y), logit);
        }
        float e = __expf(logit);
        // diag tile: s=32 pairs appear twice (lane a and lane a+32) -> keep half
        if (diag && s == 32 && l >= 32) e = 0.f;

        rowacc[8] += e; colacc[8] += e;
        #pragma unroll
        for (int q = 0; q < 8; q++) {
            rowacc[q] = fmaf(e, f[q], rowacc[q]);
            colacc[q] = fmaf(e, f[q], colacc[q]);
        }
        // rotate col accumulator so lane l tracks column (l + s_next) & 63
        if (t + 1 < nsteps) {
            const int src = (l + 8) & 63;
            #pragma unroll
            for (int q = 0; q < 9; q++) colacc[q] = __shfl(colacc[q], src);
        }
    }

    const int stag = b & 63;  // stagger scatter start to decorrelate blocks

    // ---- row-side reduce across the 4 waves, then HW-atomic scatter ----
    #pragma unroll
    for (int q = 0; q < 9; q++) part[q * 256 + w * 64 + l] = rowacc[q];
    __syncthreads();
    if (tid < 192) {
        const int sig = (tid + stag) & 63;
        #pragma unroll
        for (int r = 0; r < 3; r++) {
            const int q = (tid >> 6) * 3 + r;
            const float* pp = part + q * 256 + sig;
            unsafeAtomicAdd(&acc[(rbase + sig) * 9 + q], pp[0] + pp[64] + pp[128] + pp[192]);
        }
    }
    __syncthreads();

    // ---- col-side: un-rotate to true column index, reduce, scatter ----
    const int s_last = sbase + 8 * (nsteps - 1);
    const int cfin = (l + s_last) & 63;
    #pragma unroll
    for (int q = 0; q < 9; q++) part[q * 256 + w * 64 + cfin] = colacc[q];
    __syncthreads();
    if (tid < 192) {
        const int sig = (tid + stag) & 63;
        #pragma unroll
        for (int r = 0; r < 3; r++) {
            const int q = (tid >> 6) * 3 + r;
            const float* pp = part + q * 256 + sig;
            unsafeAtomicAdd(&acc[(cbase + sig) * 9 + q], pp[0] + pp[64] + pp[128] + pp[192]);
        }
    }
}

// ---------------- Kernel 3: overlap net per row ----------------
__global__ void out_k(const float* __restrict__ acc,
                      const float* __restrict__ ow1, const float* __restrict__ ob1,
                      const float* __restrict__ og1, const float* __restrict__ obt1,
                      const float* __restrict__ ow2, const float* __restrict__ ob2,
                      float* __restrict__ out)
{
    __shared__ float h2s[32];
    const int i = blockIdx.x, t = threadIdx.x;   // 64 threads
    if (t < 32) {
        const float invL = frcp(acc[i * 9 + 8]);
        float z2 = ob1[t];
        #pragma unroll
        for (int f = 0; f < 8; f++) z2 = fmaf(ow1[t * 8 + f], acc[i * 9 + f] * invL, z2);
        float mu = z2;
        #pragma unroll
        for (int off = 16; off > 0; off >>= 1) mu += __shfl_xor(mu, off);
        mu *= (1.f / 32.f);
        const float d = z2 - mu;
        float var = d * d;
        #pragma unroll
        for (int off = 16; off > 0; off >>= 1) var += __shfl_xor(var, off);
        var *= (1.f / 32.f);
        const float y = d * __builtin_amdgcn_rsqf(var + 1e-5f) * og1[t] + obt1[t];
        h2s[t] = 0.5f * y * (1.f + erf_div_sqrt2(y));
    }
    __syncthreads();
    if (t < 16) {
        float o = ob2[t];
        #pragma unroll
        for (int k = 0; k < 32; k++) o = fmaf(ow2[t * 32 + k], h2s[k], o);
        out[i * 16 + t] = o;
    }
}

extern "C" void kernel_launch(void* const* d_in, const int* in_sizes, int n_in,
                              void* d_out, int out_size, void* d_ws, size_t ws_size,
                              hipStream_t stream) {
    const float* p    = (const float*)d_in[0];
    const float* iw1  = (const float*)d_in[1];
    const float* ib1  = (const float*)d_in[2];
    const float* ig1  = (const float*)d_in[3];
    const float* ibt1 = (const float*)d_in[4];
    const float* iw2  = (const float*)d_in[5];
    // d_in[6] = ib2: uniform logit offset, softmax-invariant -> unused
    const float* ow1  = (const float*)d_in[7];
    const float* ob1  = (const float*)d_in[8];
    const float* og1  = (const float*)d_in[9];
    const float* obt1 = (const float*)d_in[10];
    const float* ow2  = (const float*)d_in[11];
    const float* ob2  = (const float*)d_in[12];

    float* dv  = (float*)d_ws;                 // [2048][8]
    float* acc = (float*)d_ws + N_SIG * 8;     // [2048][9] (sum e*f, sum e)

    derive_k<<<N_SIG / 256, 256, 0, stream>>>(p, dv, acc);
    pair_k<<<N_PAIR_BLOCKS, 256, 0, stream>>>(dv, iw1, ib1, ig1, ibt1, iw2, acc);
    out_k<<<N_SIG, 64, 0, stream>>>(acc, ow1, ob1, og1, obt1, ow2, ob2,
                                    (float*)d_out);
}

// Round 7
// 147.038 us; speedup vs baseline: 2.9651x; 2.7630x over previous
//
#include <hip/hip_runtime.h>

#define N_SIG 2048
#define NT    32           // 2048/64 tiles per dimension
#define N_PAIR_BLOCKS 1056 // (32*33/2) tiles * 2 half-blocks

__device__ __forceinline__ float frcp(float x) { return __builtin_amdgcn_rcpf(x); }

// erf(y / sqrt(2)) — Abramowitz–Stegun 7.1.26 with sqrt2 folded in, |err| < 1.5e-7
__device__ __forceinline__ float erf_div_sqrt2(float y) {
    const float ay = fabsf(y);
    const float t  = frcp(fmaf(0.23164454f, ay, 1.f));   // p/sqrt2, p = 0.3275911
    const float p  = t * fmaf(t, fmaf(t, fmaf(t, fmaf(t, 1.061405429f, -1.453152027f),
                                              1.421413741f), -0.284496736f), 0.254829592f);
    const float e  = __expf(-0.5f * ay * ay);
    return copysignf(fmaf(-p, e, 1.f), y);
}

// ---------------- Kernel 1: per-signal derived quantities + zero acc ----------------
__global__ void derive_k(const float* __restrict__ p, float* __restrict__ dv,
                         float* __restrict__ acc) {
    int j = blockIdx.x * blockDim.x + threadIdx.x;
    if (j >= N_SIG) return;
    #pragma unroll
    for (int k = 0; k < 9; k++) acc[j * 9 + k] = 0.f;
    const float* pj = p + j * 15;
    float m1 = pj[0] * 95.f + 5.f, m2 = pj[1] * 95.f + 5.f;
    float mc = powf(m1 * m2, 0.6f) / powf(m1 + m2, 0.2f);
    float fisco = 220.f / (m1 + m2);
    float dist = pj[2] * 2950.f + 50.f;
    float4* o = (float4*)(dv + j * 8);
    o[0] = make_float4(pj[5], pj[3], pj[4], mc);   // t, ra, dec, mc
    o[1] = make_float4(fisco, dist, pj[7], 0.f);   // fisco, dist, psi, pad
}

// ---------------- Kernel 2: symmetric pair tiles ----------------
// NOTE: no min-waves arg! (256,4) capped VGPR at 128 -> allocator squeezed to 64
// -> z[16]/colacc spilled to scratch -> 1.1 GB HBM spill traffic (rounds 5/6).
__global__ __launch_bounds__(256) void pair_k(
    const float* __restrict__ dv,
    const float* __restrict__ iw1, const float* __restrict__ ib1,
    const float* __restrict__ ig1, const float* __restrict__ ibt1,
    const float* __restrict__ iw2,
    float* __restrict__ acc)
{
    __shared__ float4 sColA[64], sColB[64];
    __shared__ __align__(16) float sW1[128];   // iw1 [16][8]
    __shared__ __align__(16) float sEC[64];    // per-h (b1, g1, bt1, 0.5*w2)
    __shared__ float part[9 * 256];            // [k][wave][lane]

    // ---- tile decode: blockIdx -> (ti <= tj) upper-triangle tile + half ----
    int b = blockIdx.x;
    int tileId = b >> 1;
    const int half = b & 1;
    int k = tileId, ti = 0;
    while (true) { int cnt = NT - ti; if (k < cnt) break; k -= cnt; ti++; }
    const int tj = ti + k;
    const int rbase = ti * 64, cbase = tj * 64;
    const bool diag = (ti == tj);

    const int tid = threadIdx.x;
    const float4* dv4 = (const float4*)dv;

    if (tid < 64)  { sColA[tid] = dv4[(cbase + tid) * 2]; sColB[tid] = dv4[(cbase + tid) * 2 + 1]; }
    if (tid >= 64 && tid < 192) sW1[tid - 64] = iw1[tid - 64];
    if (tid >= 192 && tid < 208) {
        int h = tid - 192;
        sEC[h * 4 + 0] = ib1[h]; sEC[h * 4 + 1] = ig1[h];
        sEC[h * 4 + 2] = ibt1[h]; sEC[h * 4 + 3] = 0.5f * iw2[h];
    }
    __syncthreads();

    const int w = tid >> 6, l = tid & 63;
    const int V = half * 4 + w;          // virtual wave 0..7
    const int gi = rbase + l;
    const float4 r0 = dv4[gi * 2], r1 = dv4[gi * 2 + 1];
    const float ti_ = r0.x, rai = r0.y, deci = r0.z, mci = r0.w;
    const float fi = r1.x, disti = r1.y, psii = r1.z;

    const int nsteps = diag ? 4 : 8;
    const int sbase  = diag ? (V + 1) : V;   // diag covers s in 1..32, off-diag 0..63

    float rowacc[9], colacc[9];
    #pragma unroll
    for (int q = 0; q < 9; q++) { rowacc[q] = 0.f; colacc[q] = 0.f; }

    const float4* sW4  = (const float4*)sW1;
    const float4* sEC4 = (const float4*)sEC;

    for (int t = 0; t < nsteps; t++) {
        const int s  = sbase + 8 * t;
        const int dj = (l + s) & 63;
        const float4 c0 = sColA[dj], c1 = sColB[dj];

        // ---- symmetric pairwise features ----
        const float dra  = fabsf(rai - c0.y), ddec = fabsf(deci - c0.z);
        float f[8];
        f[0] = fabsf(ti_ - c0.x);
        f[1] = __builtin_amdgcn_sqrtf(fmaf(dra, dra, ddec * ddec));
        f[2] = frcp(fmaf(fabsf(mci - c0.w), 0.033333333f, 1.f));
        f[3] = __expf(fabsf(fi - c1.x) * -0.01f);
        f[4] = fminf(disti, c1.y) * frcp(fmaxf(disti, c1.y));
        f[5] = fabsf(psii - c1.z);
        f[6] = dra; f[7] = ddec;

        // ---- 8->16 GEMV + fused moments ----
        float z[16];
        float s1 = 0.f, s2 = 0.f;
        #pragma unroll
        for (int h = 0; h < 16; h++) {
            const float4 w0 = sW4[h * 2];
            const float4 w1 = sW4[h * 2 + 1];
            float zv = sEC4[h].x;
            zv = fmaf(w0.x, f[0], zv); zv = fmaf(w0.y, f[1], zv);
            zv = fmaf(w0.z, f[2], zv); zv = fmaf(w0.w, f[3], zv);
            zv = fmaf(w1.x, f[4], zv); zv = fmaf(w1.y, f[5], zv);
            zv = fmaf(w1.z, f[6], zv); zv = fmaf(w1.w, f[7], zv);
            z[h] = zv;
            s1 += zv; s2 = fmaf(zv, zv, s2);
        }
        const float mu  = s1 * 0.0625f;
        const float var = fmaf(-mu, mu, s2 * 0.0625f);
        const float inv = __builtin_amdgcn_rsqf(var + 1e-5f);

        // ---- GELU(erf) + dot(iw2) ----
        float logit = 0.f;
        #pragma unroll
        for (int h = 0; h < 16; h++) {
            const float4 c = sEC4[h];  // (b, g, bt, 0.5*w2)
            const float y = fmaf((z[h] - mu) * inv, c.y, c.z);
            logit = fmaf(y * c.w, 1.f + erf_div_sqrt2(y), logit);
        }
        float e = __expf(logit);
        // diag tile: s=32 pairs appear twice (lane a and lane a+32) -> keep half
        if (diag && s == 32 && l >= 32) e = 0.f;

        rowacc[8] += e; colacc[8] += e;
        #pragma unroll
        for (int q = 0; q < 8; q++) {
            rowacc[q] = fmaf(e, f[q], rowacc[q]);
            colacc[q] = fmaf(e, f[q], colacc[q]);
        }
        // rotate col accumulator so lane l tracks column (l + s_next) & 63
        if (t + 1 < nsteps) {
            const int src = (l + 8) & 63;
            #pragma unroll
            for (int q = 0; q < 9; q++) colacc[q] = __shfl(colacc[q], src);
        }
    }

    const int stag = b & 63;  // stagger scatter start to decorrelate blocks

    // ---- row-side reduce across the 4 waves, then HW-atomic scatter ----
    #pragma unroll
    for (int q = 0; q < 9; q++) part[q * 256 + w * 64 + l] = rowacc[q];
    __syncthreads();
    if (tid < 192) {
        const int sig = (tid + stag) & 63;
        #pragma unroll
        for (int r = 0; r < 3; r++) {
            const int q = (tid >> 6) * 3 + r;
            const float* pp = part + q * 256 + sig;
            unsafeAtomicAdd(&acc[(rbase + sig) * 9 + q], pp[0] + pp[64] + pp[128] + pp[192]);
        }
    }
    __syncthreads();

    // ---- col-side: un-rotate to true column index, reduce, scatter ----
    const int s_last = sbase + 8 * (nsteps - 1);
    const int cfin = (l + s_last) & 63;
    #pragma unroll
    for (int q = 0; q < 9; q++) part[q * 256 + w * 64 + cfin] = colacc[q];
    __syncthreads();
    if (tid < 192) {
        const int sig = (tid + stag) & 63;
        #pragma unroll
        for (int r = 0; r < 3; r++) {
            const int q = (tid >> 6) * 3 + r;
            const float* pp = part + q * 256 + sig;
            unsafeAtomicAdd(&acc[(cbase + sig) * 9 + q], pp[0] + pp[64] + pp[128] + pp[192]);
        }
    }
}

// ---------------- Kernel 3: overlap net per row ----------------
__global__ void out_k(const float* __restrict__ acc,
                      const float* __restrict__ ow1, const float* __restrict__ ob1,
                      const float* __restrict__ og1, const float* __restrict__ obt1,
                      const float* __restrict__ ow2, const float* __restrict__ ob2,
                      float* __restrict__ out)
{
    __shared__ float h2s[32];
    const int i = blockIdx.x, t = threadIdx.x;   // 64 threads
    if (t < 32) {
        const float invL = frcp(acc[i * 9 + 8]);
        float z2 = ob1[t];
        #pragma unroll
        for (int f = 0; f < 8; f++) z2 = fmaf(ow1[t * 8 + f], acc[i * 9 + f] * invL, z2);
        float mu = z2;
        #pragma unroll
        for (int off = 16; off > 0; off >>= 1) mu += __shfl_xor(mu, off);
        mu *= (1.f / 32.f);
        const float d = z2 - mu;
        float var = d * d;
        #pragma unroll
        for (int off = 16; off > 0; off >>= 1) var += __shfl_xor(var, off);
        var *= (1.f / 32.f);
        const float y = d * __builtin_amdgcn_rsqf(var + 1e-5f) * og1[t] + obt1[t];
        h2s[t] = 0.5f * y * (1.f + erf_div_sqrt2(y));
    }
    __syncthreads();
    if (t < 16) {
        float o = ob2[t];
        #pragma unroll
        for (int k = 0; k < 32; k++) o = fmaf(ow2[t * 32 + k], h2s[k], o);
        out[i * 16 + t] = o;
    }
}

extern "C" void kernel_launch(void* const* d_in, const int* in_sizes, int n_in,
                              void* d_out, int out_size, void* d_ws, size_t ws_size,
                              hipStream_t stream) {
    const float* p    = (const float*)d_in[0];
    const float* iw1  = (const float*)d_in[1];
    const float* ib1  = (const float*)d_in[2];
    const float* ig1  = (const float*)d_in[3];
    const float* ibt1 = (const float*)d_in[4];
    const float* iw2  = (const float*)d_in[5];
    // d_in[6] = ib2: uniform logit offset, softmax-invariant -> unused
    const float* ow1  = (const float*)d_in[7];
    const float* ob1  = (const float*)d_in[8];
    const float* og1  = (const float*)d_in[9];
    const float* obt1 = (const float*)d_in[10];
    const float* ow2  = (const float*)d_in[11];
    const float* ob2  = (const float*)d_in[12];

    float* dv  = (float*)d_ws;                 // [2048][8]
    float* acc = (float*)d_ws + N_SIG * 8;     // [2048][9] (sum e*f, sum e)

    derive_k<<<N_SIG / 256, 256, 0, stream>>>(p, dv, acc);
    pair_k<<<N_PAIR_BLOCKS, 256, 0, stream>>>(dv, iw1, ib1, ig1, ibt1, iw2, acc);
    out_k<<<N_SIG, 64, 0, stream>>>(acc, ow1, ob1, og1, obt1, ow2, ob2,
                                    (float*)d_out);
}